// Round 2
// baseline (7129.566 us; speedup 1.0000x reference)
//
#include <hip/hip_runtime.h>

// ---------------------------------------------------------------------------
// FastCASSBlock: LN -> gradient-direction selector -> biGRU (input-proj fused
// into scan chunks) -> out_proj + residual.
// Workspace layout (bytes), total 102,767,104 (~98 MiB):
//   xn   f16 [65536,256]  @ 0           (33554432)
//   gray f32 [65536]      @ 33554432    (262144)
//   flag i32 [16]         @ 33816576    (256)
//   whh_f f16 [768,256]   @ 33816832    (393216)
//   whh_b f16 [768,256]   @ 34210048    (393216)
//   out_w f16 [256,512]   @ 34603264    (262144)
//   Wcomb f16 [1536,256]  @ 34865408    (786432)
//   bcomb f32 [1536]      @ 35651840    (6144)
//   ycat f16 [65536,512]  @ 35658240    (67108864)
// ---------------------------------------------------------------------------

#define L_   4096
#define CH   32     // scan chunk length (steps)
#define NCH  128    // L_/CH

typedef __attribute__((ext_vector_type(8))) _Float16 half8;
typedef __attribute__((ext_vector_type(4))) float f32x4;

__device__ __forceinline__ unsigned short f2h(float f) {
  _Float16 h = (_Float16)f;
  return __builtin_bit_cast(unsigned short, h);
}
__device__ __forceinline__ float h2f(unsigned short u) {
  return (float)__builtin_bit_cast(_Float16, u);
}
__device__ __forceinline__ float sigm(float x) {
  return __builtin_amdgcn_rcpf(1.f + __expf(-x));
}
__device__ __forceinline__ float tanhf_(float x) {
  return 1.f - 2.f * __builtin_amdgcn_rcpf(1.f + __expf(2.f * x));
}

// --------------------------- f32 -> f16 convert ----------------------------
__global__ __launch_bounds__(256) void k_f2h(const float* __restrict__ in,
                                             unsigned short* __restrict__ out,
                                             int n) {
  int i = blockIdx.x * 256 + threadIdx.x;
  if (i < n) out[i] = f2h(in[i]);
}

// ------------------- Wcomb[n,c] = sum_j wih[n,j]*in_w[j,c] -----------------
__global__ __launch_bounds__(256) void k_wcomb(const float* __restrict__ wih_f,
                                               const float* __restrict__ wih_b,
                                               const float* __restrict__ in_w,
                                               unsigned short* __restrict__ wcomb) {
  const int n = blockIdx.x;  // 0..1535
  const float* wrow = (n < 768) ? (wih_f + (long)n * 512)
                                : (wih_b + (long)(n - 768) * 512);
  const int k = threadIdx.x;  // 0..255
  float acc = 0.f;
  for (int j = 0; j < 512; ++j) acc += wrow[j] * in_w[j * 256 + k];
  wcomb[(long)n * 256 + k] = f2h(acc);
}

// ---------------- bcomb[n] = bih[n] + sum_j wih[n,j]*in_b[j] ----------------
__global__ __launch_bounds__(256) void k_bcomb(const float* __restrict__ wih_f,
                                               const float* __restrict__ wih_b,
                                               const float* __restrict__ in_b,
                                               const float* __restrict__ bih_f,
                                               const float* __restrict__ bih_b,
                                               float* __restrict__ bcomb) {
  int n = blockIdx.x * 256 + threadIdx.x;
  if (n >= 1536) return;
  const float* wrow = (n < 768) ? (wih_f + (long)n * 512)
                                : (wih_b + (long)(n - 768) * 512);
  float acc = (n < 768) ? bih_f[n] : bih_b[n - 768];
  for (int j = 0; j < 512; ++j) acc += wrow[j] * in_b[j];
  bcomb[n] = acc;
}

// --------------------------- LayerNorm + gray ------------------------------
__global__ __launch_bounds__(256) void k_ln(const float* __restrict__ x,
                                            const float* __restrict__ gamma,
                                            const float* __restrict__ beta,
                                            unsigned short* __restrict__ xn,
                                            float* __restrict__ gray) {
  const int lane = threadIdx.x & 63;
  const long pix = (long)blockIdx.x * 4 + (threadIdx.x >> 6);
  const float4 v = *(const float4*)(x + pix * 256 + lane * 4);
  float s = v.x + v.y + v.z + v.w;
  float s2 = v.x * v.x + v.y * v.y + v.z * v.z + v.w * v.w;
#pragma unroll
  for (int off = 32; off > 0; off >>= 1) {
    s += __shfl_xor(s, off, 64);
    s2 += __shfl_xor(s2, off, 64);
  }
  const float mu = s * (1.f / 256.f);
  const float var = fmaxf(s2 * (1.f / 256.f) - mu * mu, 0.f);
  const float rstd = rsqrtf(var + 1e-5f);
  const float4 gm = *(const float4*)(gamma + lane * 4);
  const float4 bt = *(const float4*)(beta + lane * 4);
  float o0 = (v.x - mu) * rstd * gm.x + bt.x;
  float o1 = (v.y - mu) * rstd * gm.y + bt.y;
  float o2 = (v.z - mu) * rstd * gm.z + bt.z;
  float o3 = (v.w - mu) * rstd * gm.w + bt.w;
  ushort4 o;
  o.x = f2h(o0); o.y = f2h(o1); o.z = f2h(o2); o.w = f2h(o3);
  *(ushort4*)(xn + pix * 256 + lane * 4) = o;
  float gs = o0 + o1 + o2 + o3;
#pragma unroll
  for (int off = 32; off > 0; off >>= 1) gs += __shfl_xor(gs, off, 64);
  if (lane == 0) gray[pix] = gs * (1.f / 256.f);
}

// --------------------- gradient-direction selector -------------------------
__device__ __forceinline__ int refl64(int m) {
  return m < 0 ? -m : (m > 63 ? 126 - m : m);
}

__global__ __launch_bounds__(256) void k_sel(const float* __restrict__ gray,
                                             const float* __restrict__ w1,
                                             const float* __restrict__ b1,
                                             const float* __restrict__ w2,
                                             const float* __restrict__ b2,
                                             int* __restrict__ flag) {
  __shared__ float g[64][65];
  __shared__ float part[4][4];
  const int b = blockIdx.x;
  const int tid = threadIdx.x;
  for (int r = 0; r < 16; ++r) {
    int p = tid + 256 * r;
    g[p >> 6][p & 63] = gray[(long)b * 4096 + p];
  }
  __syncthreads();
  const float S = 66.f / 64.f;
  float sh = 0.f, sv = 0.f, sd = 0.f, sa = 0.f;
  for (int rr = 0; rr < 16; ++rr) {
    int p = tid + 256 * rr;
    int h = p >> 6, w = p & 63;
    float srci = (h + 0.5f) * S - 0.5f;
    int i0 = (int)srci;
    float ai = srci - (float)i0;
    int i1 = i0 + 1; if (i1 > 65) i1 = 65;
    int r0 = refl64(i0 - 1), r1 = refl64(i1 - 1);
    int wl = w ? (w - 1) : 1;
    int wr2 = (w == 63) ? 62 : (w + 1);
    float GH0 = fabsf(g[r0][wr2] - g[r0][wl]);
    float GH1 = fabsf(g[r1][wr2] - g[r1][wl]);
    float ghr = GH0 + ai * (GH1 - GH0);
    float srcj = (w + 0.5f) * S - 0.5f;
    int j0 = (int)srcj;
    float aj = srcj - (float)j0;
    int j1 = j0 + 1; if (j1 > 65) j1 = 65;
    int c0 = refl64(j0 - 1), c1 = refl64(j1 - 1);
    int hu = h ? (h - 1) : 1;
    int hd = (h == 63) ? 62 : (h + 1);
    float GV0 = fabsf(g[hd][c0] - g[hu][c0]);
    float GV1 = fabsf(g[hd][c1] - g[hu][c1]);
    float gvr = GV0 + aj * (GV1 - GV0);
    float wt = ((h == 0 || h == 63) ? 2.f : 3.f) *
               ((w == 0 || w == 63) ? 2.f : 3.f);
    sh += wt * ghr;
    sv += wt * gvr;
    sd += wt * 0.5f * (ghr + gvr);
    sa += wt * fabsf(ghr - gvr);
  }
#pragma unroll
  for (int off = 32; off > 0; off >>= 1) {
    sh += __shfl_xor(sh, off, 64);
    sv += __shfl_xor(sv, off, 64);
    sd += __shfl_xor(sd, off, 64);
    sa += __shfl_xor(sa, off, 64);
  }
  if ((tid & 63) == 0) {
    part[tid >> 6][0] = sh; part[tid >> 6][1] = sv;
    part[tid >> 6][2] = sd; part[tid >> 6][3] = sa;
  }
  __syncthreads();
  if (tid == 0) {
    float sc[4];
    for (int k = 0; k < 4; ++k)
      sc[k] = (part[0][k] + part[1][k] + part[2][k] + part[3][k]) * (1.f / 36864.f);
    float logits[4];
    for (int k = 0; k < 4; ++k) logits[k] = b2[k];
    for (int j = 0; j < 32; ++j) {
      float hj = b1[j];
      for (int i = 0; i < 4; ++i) hj += sc[i] * w1[j * 4 + i];
      hj = fmaxf(hj, 0.f);
      for (int k = 0; k < 4; ++k) logits[k] += hj * w2[k * 32 + j];
    }
    int idx = 0;
    float best = logits[0];
    for (int k = 1; k < 4; ++k)
      if (logits[k] > best) { best = logits[k]; idx = k; }
    flag[b] = (idx == 1) ? 1 : 0;
  }
}

// --------------------------- out-proj GEMM ---------------------------------
// out[m,n] = sum_k ycat[m,k]*outw[n,k] + bias[n] + resid[m,n] (f32 out).
// BM=BN=128, BK=32, 256 threads (4 waves, each a 64x64 quadrant).
__global__ __launch_bounds__(256) void k_gemm(const unsigned short* __restrict__ A,
                                              const unsigned short* __restrict__ Bw,
                                              const float* __restrict__ bias,
                                              const float* __restrict__ resid,
                                              float* __restrict__ out,
                                              int K, int N) {
  __shared__ unsigned short Al[128][40];
  __shared__ unsigned short Bl[128][40];
  const int tid = threadIdx.x;
  const long m0 = (long)blockIdx.x * 128;
  const int n0 = blockIdx.y * 128;
  const int rA = tid >> 2;
  const int cp = (tid & 3) * 8;

  const unsigned short* a0p = A + (m0 + rA) * K + cp;
  const unsigned short* a1p = A + (m0 + rA + 64) * K + cp;
  const unsigned short* b0p = Bw + (long)(n0 + rA) * K + cp;
  const unsigned short* b1p = Bw + (long)(n0 + rA + 64) * K + cp;

  const int wv = tid >> 6, lane = tid & 63;
  const int wm = (wv >> 1) * 64, wn = (wv & 1) * 64;
  const int fr = lane & 15, fq = lane >> 4;

  const f32x4 zero4 = {0.f, 0.f, 0.f, 0.f};
  f32x4 acc[4][4];
#pragma unroll
  for (int i = 0; i < 4; ++i)
#pragma unroll
    for (int j = 0; j < 4; ++j) acc[i][j] = zero4;

  for (int k0 = 0; k0 < K; k0 += 32) {
    half8 va0 = *(const half8*)(a0p + k0);
    half8 va1 = *(const half8*)(a1p + k0);
    half8 vb0 = *(const half8*)(b0p + k0);
    half8 vb1 = *(const half8*)(b1p + k0);
    __syncthreads();
    *(half8*)&Al[rA][cp] = va0;
    *(half8*)&Al[rA + 64][cp] = va1;
    *(half8*)&Bl[rA][cp] = vb0;
    *(half8*)&Bl[rA + 64][cp] = vb1;
    __syncthreads();
    half8 af[4], bf[4];
#pragma unroll
    for (int i = 0; i < 4; ++i) af[i] = *(const half8*)&Al[wm + i * 16 + fr][fq * 8];
#pragma unroll
    for (int j = 0; j < 4; ++j) bf[j] = *(const half8*)&Bl[wn + j * 16 + fr][fq * 8];
#pragma unroll
    for (int i = 0; i < 4; ++i)
#pragma unroll
      for (int j = 0; j < 4; ++j)
        acc[i][j] = __builtin_amdgcn_mfma_f32_16x16x32_f16(af[i], bf[j], acc[i][j], 0, 0, 0);
  }

#pragma unroll
  for (int j = 0; j < 4; ++j) {
    const int col = n0 + wn + j * 16 + fr;
    const float bv = bias[col];
#pragma unroll
    for (int i = 0; i < 4; ++i) {
      const long mbase = m0 + wm + i * 16 + fq * 4;
#pragma unroll
      for (int r = 0; r < 4; ++r) {
        const long m = mbase + r;
        out[m * N + col] = acc[i][j][r] + bv + resid[m * N + col];
      }
    }
  }
}

// ------------------------------- GRU scan ----------------------------------
// One WG per (batch, direction): 32 WGs, 512 threads (8 waves).
// whh f16 [768,256] resident in VGPRs (192/lane). Per 32-step chunk:
//   1) dense MFMA chunk-GEMM: xp_chunk[32][768] = seq_chunk @ Wcomb_dir.T
//      (A rows gathered from xn with direction routing; B streamed from L2)
//   2) 32 sequential GRU steps: gh = h @ whh.T (M=16-padded MFMA, row 0),
//      gate math on threads 0..255, h update, y write.
__global__ __launch_bounds__(512, 2) void k_scan(
    const unsigned short* __restrict__ xn,
    const unsigned short* __restrict__ wcomb,
    const float* __restrict__ bcomb,
    const unsigned short* __restrict__ whhf,
    const unsigned short* __restrict__ whhb,
    const float* __restrict__ bhhf,
    const float* __restrict__ bhhb,
    const int* __restrict__ flag,
    unsigned short* __restrict__ ycat) {
  const int dir = blockIdx.x & 1;
  const int b = blockIdx.x >> 1;
  const unsigned short* whh = dir ? whhb : whhf;
  const float* bhh = dir ? bhhb : bhhf;
  const unsigned short* wcd = wcomb + (long)dir * (768 * 256);
  const float* bcd = bcomb + dir * 768;
  const int tid = threadIdx.x;
  const int wv = tid >> 6;
  const int lane = tid & 63;
  const int fr = lane & 15;
  const int fq = lane >> 4;
  const int fb = flag[b];

  // resident recurrent weights: wave wv owns N-tiles {wv+8j}
  half8 wf[6][8];
#pragma unroll
  for (int j = 0; j < 6; ++j) {
    const unsigned short* wrow =
        whh + (long)(((wv + 8 * j) << 4) + fr) * 256 + fq * 8;
#pragma unroll
    for (int s = 0; s < 8; ++s) wf[j][s] = *(const half8*)(wrow + s * 32);
  }

  __shared__ unsigned short xplds[CH][768];  // 48 KiB
  __shared__ unsigned short hlds[256];
  __shared__ float ghlds[768];

  float br = 0.f, bz = 0.f, bnh = 0.f, bcn = 0.f, hreg = 0.f;
  if (tid < 256) {
    hlds[tid] = 0;
    br = bhh[tid] + bcd[tid];
    bz = bhh[256 + tid] + bcd[256 + tid];
    bnh = bhh[512 + tid];
    bcn = bcd[512 + tid];
  }
  __syncthreads();

  const long xnb = (long)b * 4096;
  unsigned short* yb = ycat + (long)b * (L_ * 512) + dir * 256;

  const f32x4 zero4 = {0.f, 0.f, 0.f, 0.f};
  const half8 zero8h = {0, 0, 0, 0, 0, 0, 0, 0};

  for (int c = 0; c < NCH; ++c) {
    const int cc = dir ? (NCH - 1 - c) : c;
    const int t0 = cc * CH;

    // ---- chunk GEMM: xp_chunk = seq[t0..t0+31] @ wcd.T ----
    const unsigned short* arow0;
    const unsigned short* arow1;
    {
      int t = t0 + fr;
      int p = fb ? (((t & 63) << 6) | (t >> 6)) : t;
      arow0 = xn + (xnb + p) * 256 + fq * 8;
      t = t0 + 16 + fr;
      p = fb ? (((t & 63) << 6) | (t >> 6)) : t;
      arow1 = xn + (xnb + p) * 256 + fq * 8;
    }
#pragma unroll
    for (int hf = 0; hf < 2; ++hf) {
      f32x4 acc0[3], acc1[3];
#pragma unroll
      for (int j = 0; j < 3; ++j) { acc0[j] = zero4; acc1[j] = zero4; }
#pragma unroll
      for (int s = 0; s < 8; ++s) {
        half8 a0 = *(const half8*)(arow0 + s * 32);
        half8 a1 = *(const half8*)(arow1 + s * 32);
#pragma unroll
        for (int j = 0; j < 3; ++j) {
          const int n = wv * 96 + hf * 48 + j * 16 + fr;
          half8 bfr = *(const half8*)(wcd + (long)n * 256 + s * 32 + fq * 8);
          acc0[j] = __builtin_amdgcn_mfma_f32_16x16x32_f16(a0, bfr, acc0[j], 0, 0, 0);
          acc1[j] = __builtin_amdgcn_mfma_f32_16x16x32_f16(a1, bfr, acc1[j], 0, 0, 0);
        }
      }
#pragma unroll
      for (int j = 0; j < 3; ++j) {
        const int n = wv * 96 + hf * 48 + j * 16 + fr;
#pragma unroll
        for (int r = 0; r < 4; ++r) {
          xplds[fq * 4 + r][n] = f2h(acc0[j][r]);
          xplds[16 + fq * 4 + r][n] = f2h(acc1[j][r]);
        }
      }
    }
    __syncthreads();  // xp_chunk ready

    // ---- sequential GRU steps within chunk ----
    for (int lt = 0; lt < CH; ++lt) {
      const int ts = dir ? (CH - 1 - lt) : lt;
      float xr = 0.f, xz = 0.f, xnv = 0.f;
      if (tid < 256) {
        xr = h2f(xplds[ts][tid]);
        xz = h2f(xplds[ts][256 + tid]);
        xnv = h2f(xplds[ts][512 + tid]);
      }
      f32x4 acc[6];
#pragma unroll
      for (int s = 0; s < 8; ++s) {
        half8 a = zero8h;
        if (fr == 0) a = *(const half8*)&hlds[s * 32 + fq * 8];
#pragma unroll
        for (int j = 0; j < 6; ++j) {
          f32x4 cin = (s == 0) ? zero4 : acc[j];
          acc[j] = __builtin_amdgcn_mfma_f32_16x16x32_f16(a, wf[j][s], cin, 0, 0, 0);
        }
      }
      if (lane < 16) {
#pragma unroll
        for (int j = 0; j < 6; ++j)
          ghlds[((wv + 8 * j) << 4) + lane] = acc[j][0];
      }
      __syncthreads();
      if (tid < 256) {
        float r = sigm(xr + ghlds[tid] + br);
        float z = sigm(xz + ghlds[256 + tid] + bz);
        float n = tanhf_(xnv + bcn + r * (ghlds[512 + tid] + bnh));
        float hn = n + z * (hreg - n);
        hreg = hn;
        unsigned short hb = f2h(hn);
        hlds[tid] = hb;
        yb[(long)(t0 + ts) * 512 + tid] = hb;
      }
      __syncthreads();
    }
  }
}

// ------------------------------- launcher ----------------------------------
extern "C" void kernel_launch(void* const* d_in, const int* in_sizes, int n_in,
                              void* d_out, int out_size, void* d_ws, size_t ws_size,
                              hipStream_t stream) {
  (void)in_sizes; (void)n_in; (void)out_size; (void)ws_size;
  const float* x     = (const float*)d_in[0];
  const float* lng   = (const float*)d_in[1];
  const float* lnb   = (const float*)d_in[2];
  const float* w1    = (const float*)d_in[3];
  const float* b1    = (const float*)d_in[4];
  const float* w2    = (const float*)d_in[5];
  const float* b2    = (const float*)d_in[6];
  const float* in_w  = (const float*)d_in[7];
  const float* in_b  = (const float*)d_in[8];
  const float* wih_f = (const float*)d_in[9];
  const float* whh_f = (const float*)d_in[10];
  const float* bih_f = (const float*)d_in[11];
  const float* bhh_f = (const float*)d_in[12];
  const float* wih_b = (const float*)d_in[13];
  const float* whh_b = (const float*)d_in[14];
  const float* bih_b = (const float*)d_in[15];
  const float* bhh_b = (const float*)d_in[16];
  const float* out_w = (const float*)d_in[17];
  const float* out_b = (const float*)d_in[18];

  char* ws = (char*)d_ws;
  unsigned short* xn    = (unsigned short*)(ws + 0);
  float*          gray  = (float*)(ws + 33554432);
  int*            flag  = (int*)(ws + 33816576);
  unsigned short* whhf16 = (unsigned short*)(ws + 33816832);
  unsigned short* whhb16 = (unsigned short*)(ws + 34210048);
  unsigned short* outw16 = (unsigned short*)(ws + 34603264);
  unsigned short* wcomb  = (unsigned short*)(ws + 34865408);
  float*          bcomb  = (float*)(ws + 35651840);
  unsigned short* ycat   = (unsigned short*)(ws + 35658240);

  k_f2h<<<768, 256, 0, stream>>>(whh_f, whhf16, 196608);
  k_f2h<<<768, 256, 0, stream>>>(whh_b, whhb16, 196608);
  k_f2h<<<512, 256, 0, stream>>>(out_w, outw16, 131072);
  k_wcomb<<<1536, 256, 0, stream>>>(wih_f, wih_b, in_w, wcomb);
  k_bcomb<<<6, 256, 0, stream>>>(wih_f, wih_b, in_b, bih_f, bih_b, bcomb);
  k_ln<<<16384, 256, 0, stream>>>(x, lng, lnb, xn, gray);
  k_sel<<<16, 256, 0, stream>>>(gray, w1, b1, w2, b2, flag);
  k_scan<<<32, 512, 0, stream>>>(xn, wcomb, bcomb, whhf16, whhb16,
                                 bhh_f, bhh_b, flag, ycat);
  dim3 gout(512, 2);
  k_gemm<<<gout, 256, 0, stream>>>(ycat, outw16, out_b, x, (float*)d_out, 512, 256);
}